// Round 4
// baseline (297.346 us; speedup 1.0000x reference)
//
#include <hip/hip_runtime.h>

// DilatedConv1D: out[b,o,p] = bias[o] + sum_c x[b,c,p]*W[o,c,0] + x[b,c,p+2]*W[o,c,1]
// x: (8,128,32768) fp32, W: (128,128,2) fp32, bias: (128) fp32, out: (8,128,32769) fp32.
//
// Round-8: channel-residue-complete streaming.
//  Theory: all prior kernels read 256B granules at exact 2^17-byte strides with
//  p-offsets quantized so concurrent requests cover few HBM channel residues ->
//  hard ~2.2 TB/s ceiling regardless of structure. Now:
//  * 256 blocks (1/CU, 512 thr), block g owns tiles {g,g+32,g+64,g+96} of 256 pos:
//    p_byte = (g+32i)*1024 -> channel residue 4g+granule, phase-independent ->
//    full residue coverage even in lockstep; 1KB contiguous reads per channel-row.
//  * K-chunked two-hop staging: HBM -(global_load_lds, 16c x 1KB rows)-> fp32
//    ring-of-4 -> convert -> single bf16 [pos][c] tile (K=128 resident) -> MFMA.
//  * Counted per-wave vmcnt (2 chunks lookahead, 3rd issued post-convert) keeps
//    34-51 KB/CU in flight continuously, including across the MFMA phase.
//    One vmcnt(0) per tile (post-stores) keeps wait immediates deterministic.
//  * fp32 pitch 260 / bf16 pitch 136: all ds_read_b128 patterns conflict-free.

namespace {

constexpr int kC   = 128;
constexpr int kT   = 32768;
constexpr int kP   = kT + 1;
constexpr int kOut = 128;
constexpr int kTileP  = 256;                 // positions per tile
constexpr int kTPB    = 4;                   // tiles per block (strided by 32)
constexpr int kGroups = 32;                  // blocks per batch
constexpr int kNBlocks = 8 * kGroups;        // 256 = 1 per CU
constexpr int kChunks = 8;                   // 16-channel chunks per tile
constexpr int kQ      = kTPB * kChunks;      // 32 flattened chunk steps
constexpr int kRowF   = 260;                 // fp32 buf row pitch (floats) -> CF banks
constexpr int kBufF   = 16 * kRowF + 64;     // 4224 floats per chunk buffer (halo at +4160)
constexpr int kPitch  = 136;                 // bf16 tile pitch (shorts) -> CF banks
constexpr int kXSRows = kTileP + 2;          // 258 (2 halo rows for tap 1)

typedef __attribute__((ext_vector_type(8))) short short8;
typedef __attribute__((ext_vector_type(4))) float f32x4;

// float -> bf16 bits, round-to-nearest-even (finite inputs)
__device__ __forceinline__ short f2bf(float f) {
    unsigned int u = __builtin_bit_cast(unsigned int, f);
    u += 0x7fffu + ((u >> 16) & 1u);
    return (short)(u >> 16);
}

// Async global->LDS DMA. Dest = wave-uniform base + lane*size.
__device__ __forceinline__ void dma16(const float* g, float* l) {
    __builtin_amdgcn_global_load_lds(
        (const __attribute__((address_space(1))) void*)g,
        (__attribute__((address_space(3))) void*)l, 16, 0, 0);
}
__device__ __forceinline__ void dma4(const float* g, float* l) {
    __builtin_amdgcn_global_load_lds(
        (const __attribute__((address_space(1))) void*)g,
        (__attribute__((address_space(3))) void*)l, 4, 0, 0);
}

// Issue one 16-channel chunk: 16 x 1KB contiguous row reads (2 per wave) + halo
// (wave 7). ~17 KB, zero VGPR cost while in flight.
__device__ __forceinline__ void issue_chunk(const float* __restrict__ xb, int p0,
                                            int ch, float* __restrict__ buf,
                                            int wv, int lane, bool last) {
    #pragma unroll
    for (int rr = 0; rr < 2; ++rr) {
        const int r = 2 * wv + rr;
        const int c = ch * 16 + r;
        dma16(xb + (size_t)c * kT + p0 + lane * 4, buf + r * kRowF);
    }
    if (wv == 7) {
        // halo: pos p0+256..259 for 16 channels (overread 2 pos; last tile clamps
        // in-bounds, values zeroed at convert).
        const int hc = ch * 16 + (lane >> 2);
        const int hp = last ? p0 : (p0 + kTileP);
        dma4(xb + (size_t)hc * kT + hp + (lane & 3), buf + 16 * kRowF);
    }
}

// fp32 chunk -> bf16 [pos][c] columns. Thread: c = tid&15, pos-quads tid>>4 and +32.
__device__ __forceinline__ void convert_chunk(const float* __restrict__ buf,
                                              short* __restrict__ xs,
                                              int ch, int tid, bool last) {
    const int c  = tid & 15;
    const int pq = tid >> 4;                 // 0..31
    const int cc = ch * 16 + c;
    #pragma unroll
    for (int half = 0; half < 2; ++half) {
        const int q = pq + half * 32;        // pos quad 0..63
        const f32x4 v = *reinterpret_cast<const f32x4*>(buf + c * kRowF + q * 4);
        #pragma unroll
        for (int i = 0; i < 4; ++i) {
            xs[(q * 4 + i) * kPitch + cc] = f2bf(v[i]);
        }
    }
    if (tid < 16) {                          // halo rows 256,257
        const float h0 = buf[16 * kRowF + tid * 4 + 0];
        const float h1 = buf[16 * kRowF + tid * 4 + 1];
        xs[256 * kPitch + ch * 16 + tid] = last ? (short)0 : f2bf(h0);
        xs[257 * kPitch + ch * 16 + tid] = last ? (short)0 : f2bf(h1);
    }
}

#define WAIT_VM_CHUNKS()                                            \
    do {                                                            \
        if (wv == 7) asm volatile("s_waitcnt vmcnt(6)" ::: "memory"); \
        else         asm volatile("s_waitcnt vmcnt(4)" ::: "memory"); \
    } while (0)

__global__ __launch_bounds__(512, 2) void dconv_mfma(
    const float* __restrict__ x, const float* __restrict__ W,
    const float* __restrict__ bias, float* __restrict__ out)
{
    __shared__ __align__(16) short xs[kXSRows * kPitch];   // 70,176 B
    __shared__ __align__(16) float xf[4 * kBufF];          // 67,584 B

    const int tid  = threadIdx.x;
    const int lane = tid & 63;
    const int wv   = tid >> 6;
    const int blk  = blockIdx.x;
    const int bb   = blk >> 5;                // batch
    const int g    = blk & 31;                // tile group: tiles g+32i

    const float* xb = x + (size_t)bb * kC * kT;
    float* ob = out + (size_t)bb * kOut * kP;

    // Trivial last column out[b][o][32768] = bias[o] (both taps hit the pad).
    if (g == 0 && tid < kOut) {
        ob[(size_t)tid * kP + kT] = bias[tid];
    }

    // ---------------- W fragments + bias (loads fully consumed before any chunk
    // DMA is issued, so the in-loop vmcnt queue holds only our DMA/stores). ----
    const int ogrp = wv & 1;                  // o-half  [64*ogrp, 64*ogrp+64)
    const int pgrp = wv >> 1;                 // p-quarter [64*pgrp, ...)
    short8 wf[2][4][4];                       // [tap][ofrag][kstep]
    #pragma unroll
    for (int of = 0; of < 4; ++of) {
        const int o = ogrp * 64 + of * 16 + (lane & 15);
        #pragma unroll
        for (int ks = 0; ks < 4; ++ks) {
            const int cb = ks * 32 + (lane >> 4) * 8;
            const f32x4* wp = reinterpret_cast<const f32x4*>(W + o * (kC * 2) + cb * 2);
            f32x4 wr[4];
            #pragma unroll
            for (int q = 0; q < 4; ++q) wr[q] = wp[q];
            short8 f0, f1;
            #pragma unroll
            for (int q = 0; q < 4; ++q) {
                f0[q * 2 + 0] = f2bf(wr[q][0]);  f1[q * 2 + 0] = f2bf(wr[q][1]);
                f0[q * 2 + 1] = f2bf(wr[q][2]);  f1[q * 2 + 1] = f2bf(wr[q][3]);
            }
            wf[0][of][ks] = f0;
            wf[1][of][ks] = f1;
        }
    }
    float bv[4];
    #pragma unroll
    for (int of = 0; of < 4; ++of) bv[of] = bias[ogrp * 64 + of * 16 + (lane & 15)];

    // ---------------- prologue: 3 chunks in flight ----------------
    #pragma unroll
    for (int q = 0; q < 3; ++q) {
        const int tq = q >> 3, ch = q & 7;                 // tq==0 here
        const int p0 = (g + 32 * tq) * kTileP;
        issue_chunk(xb, p0, ch, xf + (q & 3) * kBufF, wv, lane,
                    (g == 31) && (tq == kTPB - 1));
    }

    // ---------------- main loop: 4 tiles x 8 chunks ----------------
    #pragma unroll 1
    for (int t = 0; t < kTPB; ++t) {
        const int p0 = (g + 32 * t) * kTileP;
        const bool lastT = (g == 31) && (t == kTPB - 1);

        #pragma unroll 1
        for (int j = 0; j < kChunks; ++j) {
            const int q = t * kChunks + j;
            WAIT_VM_CHUNKS();                       // chunk q landed (2 in flight)
            __builtin_amdgcn_s_barrier();           // ... for every wave
            convert_chunk(xf + (q & 3) * kBufF, xs, j, tid, lastT);
            asm volatile("s_waitcnt lgkmcnt(0)" ::: "memory");
            __builtin_amdgcn_s_barrier();           // chunk q converted everywhere
            const int qn = q + 3;
            if (qn < kQ) {                          // refill ring (buffer of q-1)
                const int tq = qn >> 3, ch = qn & 7;
                const int pn = (g + 32 * tq) * kTileP;
                issue_chunk(xb, pn, ch, xf + (qn & 3) * kBufF, wv, lane,
                            (g == 31) && (tq == kTPB - 1));
            }
        }
        // bf16 tile t complete; chunks of tile t+1 streaming in under the MFMA.

        // ---------------- MFMA: D = x*W, K=128; row=pos, col=o ----------------
        f32x4 acc[4][4];                            // [pfrag][ofrag]
        #pragma unroll
        for (int pf = 0; pf < 4; ++pf)
            #pragma unroll
            for (int of = 0; of < 4; ++of)
                #pragma unroll
                for (int rr = 0; rr < 4; ++rr) acc[pf][of][rr] = bv[of];

        #pragma unroll
        for (int ks = 0; ks < 4; ++ks) {
            const int cb = ks * 32 + (lane >> 4) * 8;
            #pragma unroll
            for (int tap = 0; tap < 2; ++tap) {
                #pragma unroll
                for (int pf = 0; pf < 4; ++pf) {
                    const int pos = pgrp * 64 + pf * 16 + (lane & 15) + 2 * tap;
                    const short8 xfr =
                        *reinterpret_cast<const short8*>(xs + pos * kPitch + cb);
                    #pragma unroll
                    for (int of = 0; of < 4; ++of) {
                        acc[pf][of] = __builtin_amdgcn_mfma_f32_16x16x32_bf16(
                            xfr, wf[tap][of][ks], acc[pf][of], 0, 0, 0);
                    }
                }
            }
        }

        // ---------------- stores: 16B per (pf,of); rows 4B-aligned -> memcpy ----
        {
            const int prow = pgrp * 64 + (lane >> 4) * 4;
            const int o0   = ogrp * 64 + (lane & 15);
            #pragma unroll
            for (int pf = 0; pf < 4; ++pf) {
                const int p = p0 + prow + pf * 16;
                #pragma unroll
                for (int of = 0; of < 4; ++of) {
                    __builtin_memcpy(ob + (size_t)(o0 + of * 16) * kP + p,
                                     &acc[pf][of], sizeof(f32x4));
                }
            }
        }

        // Drain stores (+ residual chunk DMAs) so in-loop vmcnt immediates stay
        // deterministic; bf16 tile then free for the next tile's converts.
        asm volatile("s_waitcnt vmcnt(0)" ::: "memory");
        __builtin_amdgcn_s_barrier();
    }
}

}  // namespace

extern "C" void kernel_launch(void* const* d_in, const int* in_sizes, int n_in,
                              void* d_out, int out_size, void* d_ws, size_t ws_size,
                              hipStream_t stream) {
    const float* x    = (const float*)d_in[0];
    const float* W    = (const float*)d_in[1];
    const float* bias = (const float*)d_in[2];
    float* out        = (float*)d_out;

    dim3 grid(kNBlocks);   // 256 blocks = 1 per CU, 4 strided tiles each
    dim3 block(512);
    hipLaunchKernelGGL(dconv_mfma, grid, block, 0, stream, x, W, bias, out);
}